// Round 2
// baseline (22808.490 us; speedup 1.0000x reference)
//
#include <hip/hip_runtime.h>
#include <cstdint>
#include <cstddef>

// ---------------------------------------------------------------------------
// MDHP-LSTM on MI355X.  S=512, B=128, D=256, H=512.
// Round-4: XCD-local L2 handshake, rebuilt on bedrock semantics.
//   * ws shrunk 104MB -> 37.5MB (hbuf = depth-4 ring; counters not flags).
//   * Poll = atomic fetch_add(+0) at WORKGROUP scope: RMWs execute at the
//     XCD L2 (L1 has no atomic path) -> cannot L1-stale-deadlock.
//   * tid0 polls, waves released via LDS `ready` word (no extra barrier).
//   * Producer: per-wave vmcnt(0) -> LDS wave counter -> last wave incs
//     cnt (workgroup/L2) AND cnt2 (agent, fire-and-forget shadow).
//   * Bounded-spin sticky escape to agent cnt2 poll: deadlock-proof.
//   * h ring read with sc0 (L1-bypass) loads; same-XCD L2 holds fresh data.
//   * Fallback (chain spans XCDs): agent stores + sc0 sc1 loads, as round 0.
// ---------------------------------------------------------------------------

typedef __attribute__((ext_vector_type(8))) short short8;
typedef __attribute__((ext_vector_type(4))) float floatx4;

#define SEQ 512
#define BATCH 128
#define DIN 256
#define HID 512
#define KTOT 768
#define NCHAIN 8
#define NCOLW 32
#define BS_STRIDE 776         // shorts per LDS B-row (768 + 8 pad, 16B aligned)
#define HRING 4               // h ring depth (max slot skew is 2)

__device__ __forceinline__ short f2bf(float f) {
  union { float f; unsigned u; } v; v.f = f;
  unsigned u = v.u + 0x7fffu + ((v.u >> 16) & 1u);   // RNE
  return (short)(u >> 16);
}
__device__ __forceinline__ float fsig(float x) {
  return 1.f / (1.f + __expf(-x));
}
__device__ __forceinline__ float ftanh(float x) {
  float a = fabsf(x);
  float e = __expf(-2.f * a);
  float r = (1.f - e) / (1.f + e);
  return copysignf(r, x);
}

// ---- prep: GT[n][k] = bf16 of (k<256 ? W_g[k][hc] : U_g[k-256][hc]), n=g*512+hc
__global__ void prep_gt(const float* __restrict__ Wi, const float* __restrict__ Ui,
                        const float* __restrict__ Wf, const float* __restrict__ Uf,
                        const float* __restrict__ Wc, const float* __restrict__ Uc,
                        const float* __restrict__ Wo, const float* __restrict__ Uo,
                        short* __restrict__ GT) {
  int idx = blockIdx.x * 256 + threadIdx.x;
  if (idx >= 2048 * KTOT) return;
  int n = idx / KTOT, k = idx % KTOT;
  int g = n >> 9, hc = n & 511;
  const float* W; const float* U;
  if (g == 0)      { W = Wi; U = Ui; }
  else if (g == 1) { W = Wf; U = Uf; }
  else if (g == 2) { W = Wc; U = Uc; }
  else             { W = Wo; U = Uo; }
  float v = (k < DIN) ? W[k * HID + hc] : U[(k - DIN) * HID + hc];
  GT[idx] = f2bf(v);
}

// ---- prep: x -> bf16 (4 elems/thread)
__global__ void prep_xb(const float* __restrict__ x, short* __restrict__ xb) {
  int idx = blockIdx.x * 256 + threadIdx.x;           // 4,194,304
  float4 v = ((const float4*)x)[idx];
  short4 o; o.x = f2bf(v.x); o.y = f2bf(v.y); o.z = f2bf(v.z); o.w = f2bf(v.w);
  ((short4*)xb)[idx] = o;
}

// ---- prep: h0 -> hbuf ring slot 0 (bf16)
__global__ void prep_h0(const float* __restrict__ h0, short* __restrict__ hbuf) {
  int idx = blockIdx.x * 256 + threadIdx.x;           // 65536
  hbuf[idx] = f2bf(h0[idx]);
}

// ---- prep: mdhp[b][h] = tanh(alpha@A - (beta*tspan)@B + theta@C)  (fp32)
__global__ void prep_mdhp(const float* __restrict__ alpha, const float* __restrict__ beta,
                          const float* __restrict__ theta, const float* __restrict__ tspan,
                          const float* __restrict__ A, const float* __restrict__ Bm,
                          const float* __restrict__ C, float* __restrict__ mdhp) {
  int idx = blockIdx.x * 256 + threadIdx.x;           // 65536
  int b = idx >> 9, h = idx & 511;
  float ts = tspan[b];
  float acc = 0.f;
  for (int k = 0; k < 256; ++k)
    acc += alpha[b * 256 + k] * A[k * HID + h] - ts * beta[b * 256 + k] * Bm[k * HID + h];
  for (int k = 0; k < 16; ++k)
    acc += theta[b * 16 + k] * C[k * HID + h];
  mdhp[idx] = tanhf(acc);
}

// ---- zero sync state (must run every launch: graph replays)
__global__ void zero_sync(int* __restrict__ cnt, int* __restrict__ cnt2,
                          unsigned* __restrict__ det) {
  int idx = blockIdx.x * 256 + threadIdx.x;           // grid 16*256 = 4096
  if (idx < NCHAIN * SEQ) { cnt[idx] = 0; cnt2[idx] = 0; }
  if (idx < 264) det[idx] = 0;
}

// ---- the persistent recurrence kernel --------------------------------------
__global__ __launch_bounds__(256, 1) void lstm_persist(
    const short* __restrict__ xb, const float* __restrict__ c0,
    const float* __restrict__ bi, const float* __restrict__ bf_,
    const float* __restrict__ bc, const float* __restrict__ bo,
    const short* __restrict__ GT, const float* __restrict__ mdhp,
    int* cnt, int* cnt2, unsigned* det, short* hbuf, float* out) {
  __shared__ __align__(16) short Bs[64 * BS_STRIDE];   // 99,328 B
  __shared__ float gbuf[2][4][16][17];                 // dbuf by t&1: 8,704 B
  __shared__ int wv[SEQ];                              // per-step wave counter
  __shared__ int ready;                                // latest step released
  __shared__ int s_mode;

  const int tid = threadIdx.x;
  const int wg = blockIdx.x;
  const int chain = wg & 7;        // XCD-local under round-robin wg->XCD
  const int j = wg >> 3;           // 0..31 column group

  // stage B^T slice: local row lr = g*16+c  <-  GT row n = g*512 + j*16 + c
  for (int idx = tid; idx < 64 * 384; idx += 256) {
    int lr = idx / 384, dw = idx % 384;
    int n = ((lr >> 4) << 9) + (j << 4) + (lr & 15);
    ((int*)Bs)[lr * 388 + dw] = ((const int*)GT)[n * 384 + dw];
  }
  for (int i = tid; i < SEQ; i += 256) wv[i] = 0;
  if (tid == 0) ready = 0;

  // per-thread epilogue state in registers
  const int er = tid >> 4, ec = tid & 15;
  const int brow = (chain << 4) + er, hcol = (j << 4) + ec;
  float creg = c0[brow * HID + hcol];
  const float mdv = mdhp[brow * HID + hcol];
  const float b0 = bi[hcol], b1 = bf_[hcol], b2 = bc[hcol], b3 = bo[hcol];

  // ---- XCD homogeneity detection (agent-scope; one-time) -------------------
  unsigned xid;
  asm volatile("s_getreg_b32 %0, hwreg(HW_REG_XCC_ID)" : "=s"(xid));
  xid &= 15u;
  if (tid == 0) {
    __hip_atomic_store(&det[wg], xid, __ATOMIC_RELAXED, __HIP_MEMORY_SCOPE_AGENT);
    __hip_atomic_fetch_add((int*)&det[256 + chain], 1, __ATOMIC_RELEASE,
                           __HIP_MEMORY_SCOPE_AGENT);
    while (__hip_atomic_load((int*)&det[256 + chain], __ATOMIC_ACQUIRE,
                             __HIP_MEMORY_SCOPE_AGENT) < NCOLW)
      __builtin_amdgcn_s_sleep(2);
    unsigned x0 = __hip_atomic_load(&det[chain], __ATOMIC_RELAXED,
                                    __HIP_MEMORY_SCOPE_AGENT);
    int ok = 1;
    for (int jj = 1; jj < NCOLW; ++jj)
      ok &= (__hip_atomic_load(&det[chain + 8 * jj], __ATOMIC_RELAXED,
                               __HIP_MEMORY_SCOPE_AGENT) == x0);
    s_mode = ok;
  }
  __syncthreads();                            // also covers Bs / wv staging
  const bool xloc = (s_mode != 0);

  const int lane = tid & 63;
  const int g = tid >> 6;                 // wave = gate
  const int mr = lane & 15;               // A-row / B-col within tile
  const int q = lane >> 4;                // quad
  const int bglob = (chain << 4) + mr;
  const short* Brow = &Bs[(g * 16 + mr) * BS_STRIDE + q * 8];
  int* mycnt = cnt + chain * SEQ;
  int* mycnt2 = cnt2 + chain * SEQ;
  bool esc = false;                       // sticky escape to agent polling

  for (int t = 0; t < SEQ; ++t) {
    // ---- issue x A-frag loads (h-independent; in flight across the poll)
    const short* xr = xb + ((size_t)t * BATCH + bglob) * DIN + q * 8;
    short8 xaf[8];
#pragma unroll
    for (int kk = 0; kk < 8; ++kk) xaf[kk] = *(const short8*)(xr + kk * 32);

    // ---- wait for h_{t-1}: tid0 polls (L2-executed atomic RMW), LDS fan-out
    if (t > 0) {
      if (tid == 0) {
        int sp = 0;
        for (;;) {
          int v;
          if (xloc && !esc)
            v = __hip_atomic_fetch_add(&mycnt[t - 1], 0, __ATOMIC_RELAXED,
                                       __HIP_MEMORY_SCOPE_WORKGROUP);
          else
            v = __hip_atomic_load(&mycnt2[t - 1], __ATOMIC_ACQUIRE,
                                  __HIP_MEMORY_SCOPE_AGENT);
          if (v >= NCOLW) break;
          __builtin_amdgcn_s_sleep(1);
          if (++sp > 100000) esc = true;   // deadlock-proof escape hatch
        }
        __hip_atomic_store(&ready, t, __ATOMIC_RELEASE,
                           __HIP_MEMORY_SCOPE_WORKGROUP);
      }
      while (__hip_atomic_load(&ready, __ATOMIC_ACQUIRE,
                               __HIP_MEMORY_SCOPE_WORKGROUP) < t) {}
      __builtin_amdgcn_sched_barrier(0);
    }

    // ---- issue h A-frag loads from ring slot t&3 (sc0: L1-bypass, L2-hit)
    const short* hr = hbuf + (((size_t)(t & 3) * BATCH + bglob) * HID) + q * 8;
    short8 haf[16];
    if (xloc) {
#pragma unroll
      for (int kk = 0; kk < 16; ++kk)
        asm volatile("global_load_dwordx4 %0, %1, off sc0"
                     : "=v"(haf[kk]) : "v"(hr + kk * 32));
    } else {
#pragma unroll
      for (int kk = 0; kk < 16; ++kk)
        asm volatile("global_load_dwordx4 %0, %1, off sc0 sc1"
                     : "=v"(haf[kk]) : "v"(hr + kk * 32));
    }

    floatx4 ax  = {0.f, 0.f, 0.f, 0.f};
    floatx4 ah0 = {0.f, 0.f, 0.f, 0.f};
    floatx4 ah1 = {0.f, 0.f, 0.f, 0.f};

    // ---- x @ W MFMAs (overlap h-load latency)
#pragma unroll
    for (int kk = 0; kk < 8; ++kk)
      ax = __builtin_amdgcn_mfma_f32_16x16x32_bf16(
          xaf[kk], *(const short8*)(Brow + kk * 32), ax, 0, 0, 0);

    // ---- h loads landed (rule #18: waitcnt asm + sched_barrier)
    asm volatile("s_waitcnt vmcnt(0)" ::: "memory");
    __builtin_amdgcn_sched_barrier(0);

    // ---- h @ U MFMAs, two independent chains for latency
#pragma unroll
    for (int kk = 0; kk < 8; ++kk) {
      ah0 = __builtin_amdgcn_mfma_f32_16x16x32_bf16(
          haf[kk], *(const short8*)(Brow + DIN + kk * 32), ah0, 0, 0, 0);
      ah1 = __builtin_amdgcn_mfma_f32_16x16x32_bf16(
          haf[8 + kk], *(const short8*)(Brow + DIN + (8 + kk) * 32), ah1, 0, 0, 0);
    }

    // ---- epilogue: C/D layout col=lane&15, row=q*4+i (m89); gbuf dbuf'd
    const int p = t & 1;
#pragma unroll
    for (int i = 0; i < 4; ++i)
      gbuf[p][g][q * 4 + i][mr] = ax[i] + ah0[i] + ah1[i];
    __syncthreads();                         // the ONE barrier per step
    {
      float gi = gbuf[p][0][er][ec] + b0;
      float gf = gbuf[p][1][er][ec] + b1;
      float gc = gbuf[p][2][er][ec] + b2;
      float go = gbuf[p][3][er][ec] + b3;
      float it = fsig(gi), ft = fsig(gf), ot = fsig(go);
      float ch = ftanh(gc);
      float cn = mdv * (ft * creg + it * ch);
      creg = cn;
      float hv = ot * ftanh(cn);

      // bf16 ring-buffer store first (oldest in vmcnt): pair lanes -> 4B store
      unsigned hb = (unsigned)(unsigned short)f2bf(hv);
      unsigned other = (unsigned)__shfl_xor((int)hb, 1, 64);
      if ((tid & 1) == 0) {
        unsigned pack = hb | (other << 16);
        size_t hidx = (((size_t)((t + 1) & 3) * BATCH + brow) * HID) + hcol;
        if (xloc)
          *(unsigned*)&hbuf[hidx] = pack;       // plain -> shared XCD L2
        else
          __hip_atomic_store((unsigned*)&hbuf[hidx], pack, __ATOMIC_RELAXED,
                             __HIP_MEMORY_SCOPE_AGENT);
      }

      // fp32 output (not read by consumers)
      size_t oidx = ((size_t)t * BATCH + brow) * HID + hcol;
      out[oidx] = hv;
      if (t == SEQ - 1) {
        size_t base = (size_t)SEQ * BATCH * HID;
        int e = brow * HID + hcol;
        out[base + e] = hv;                    // h_T
        out[base + BATCH * HID + e] = cn;      // c_T
      }
    }

    // ---- per-wave publish: drain stores, LDS count, last wave incs counters
    if (t < SEQ - 1) {
      asm volatile("s_waitcnt vmcnt(0)" ::: "memory");
      if (lane == 0) {
        int old = __hip_atomic_fetch_add(&wv[t], 1, __ATOMIC_RELAXED,
                                         __HIP_MEMORY_SCOPE_WORKGROUP);
        if (old == 3) {                         // last wave of this WG
          if (xloc) {
            __hip_atomic_fetch_add(&mycnt[t], 1, __ATOMIC_RELAXED,
                                   __HIP_MEMORY_SCOPE_WORKGROUP);   // L2
            __hip_atomic_fetch_add(&mycnt2[t], 1, __ATOMIC_RELAXED,
                                   __HIP_MEMORY_SCOPE_AGENT);       // shadow
          } else {
            __hip_atomic_fetch_add(&mycnt2[t], 1, __ATOMIC_RELEASE,
                                   __HIP_MEMORY_SCOPE_AGENT);
          }
        }
      }
    }
  }
}

// ---------------------------------------------------------------------------
extern "C" void kernel_launch(void* const* d_in, const int* in_sizes, int n_in,
                              void* d_out, int out_size, void* d_ws, size_t ws_size,
                              hipStream_t stream) {
  const float* x     = (const float*)d_in[0];
  const float* h0    = (const float*)d_in[1];
  const float* c0    = (const float*)d_in[2];
  const float* alpha = (const float*)d_in[3];
  const float* beta  = (const float*)d_in[4];
  const float* theta = (const float*)d_in[5];
  const float* tspan = (const float*)d_in[6];
  const float* Amd   = (const float*)d_in[7];
  const float* Bmd   = (const float*)d_in[8];
  const float* Cmd   = (const float*)d_in[9];
  const float* Wi = (const float*)d_in[10]; const float* Ui = (const float*)d_in[11];
  const float* bi = (const float*)d_in[12];
  const float* Wf = (const float*)d_in[13]; const float* Uf = (const float*)d_in[14];
  const float* bf_ = (const float*)d_in[15];
  const float* Wc = (const float*)d_in[16]; const float* Uc = (const float*)d_in[17];
  const float* bc = (const float*)d_in[18];
  const float* Wo = (const float*)d_in[19]; const float* Uo = (const float*)d_in[20];
  const float* bo = (const float*)d_in[21];

  float* out = (float*)d_out;
  char* ws = (char*)d_ws;
  // ws layout (bytes):
  short* GT     = (short*)ws;                         // @0          3,145,728
  float* mdhp   = (float*)(ws + 3145728);             // @3,145,728    262,144
  int*   cnt    = (int*)(ws + 3407872);               // @3,407,872     16,384
  int*   cnt2   = (int*)(ws + 3424256);               // @3,424,256     16,384
  unsigned* det = (unsigned*)(ws + 3440640);          // @3,440,640      4,096
  short* xb     = (short*)(ws + 3444736);             // @3,444,736 33,554,432
  short* hbuf   = (short*)(ws + 36999168);            // @36,999,168   524,288
  // total: 37,523,456 B  (proven capacity >= 104 MB)

  zero_sync<<<16, 256, 0, stream>>>(cnt, cnt2, det);
  prep_gt<<<(2048 * KTOT + 255) / 256, 256, 0, stream>>>(Wi, Ui, Wf, Uf, Wc, Uc, Wo, Uo, GT);
  prep_xb<<<16384, 256, 0, stream>>>(x, xb);
  prep_h0<<<256, 256, 0, stream>>>(h0, hbuf);
  prep_mdhp<<<256, 256, 0, stream>>>(alpha, beta, theta, tspan, Amd, Bmd, Cmd, mdhp);
  lstm_persist<<<NCHAIN * NCOLW, 256, 0, stream>>>(xb, c0, bi, bf_, bc, bo,
                                                   GT, mdhp, cnt, cnt2, det, hbuf, out);
}

// Round 3
// 2403.842 us; speedup vs baseline: 9.4883x; 9.4883x over previous
//
#include <hip/hip_runtime.h>
#include <cstdint>
#include <cstddef>

// ---------------------------------------------------------------------------
// MDHP-LSTM on MI355X.  S=512, B=128, D=256, H=512.
// Round-5: XCD-local handshake via ASM L2 atomics (no C++ scope games).
//   * Poll/publish = inline-asm global_atomic_add WITHOUT sc1 -> executes in
//     the XCD-local L2 (TCC). Atomics never consult L1 -> no staleness; asm
//     "memory" -> no compiler hoisting (round-2 failure mode eliminated).
//   * h: full-size hbuf (slot t = h_{t-1}), plain stores + plain loads.
//     Fresh address each step -> L1 cold; same-XCD L2 serves dirty data.
//     Proven in round 0 (agent) and round 2 (plain/L2-resident).
//   * Escape hatch: 4000 spins -> sticky fallback to RELAXED agent poll of
//     shadow counter cnt2 (round-0-proven). Publishers inc cnt (L2 asm) AND
//     cnt2 (agent) in fast mode.
//   * Fallback mode (chain spans XCDs): round-0 protocol exactly.
//   * ws = 104.11 MB  (< 104.21 MB proven in round 0).
// ---------------------------------------------------------------------------

typedef __attribute__((ext_vector_type(8))) short short8;
typedef __attribute__((ext_vector_type(4))) float floatx4;

#define SEQ 512
#define BATCH 128
#define DIN 256
#define HID 512
#define KTOT 768
#define NCHAIN 8
#define NCOLW 32
#define BS_STRIDE 776         // shorts per LDS B-row (768 + 8 pad, 16B aligned)

__device__ __forceinline__ short f2bf(float f) {
  union { float f; unsigned u; } v; v.f = f;
  unsigned u = v.u + 0x7fffu + ((v.u >> 16) & 1u);   // RNE
  return (short)(u >> 16);
}
__device__ __forceinline__ float fsig(float x) {
  return 1.f / (1.f + __expf(-x));
}
__device__ __forceinline__ float ftanh(float x) {
  float a = fabsf(x);
  float e = __expf(-2.f * a);
  float r = (1.f - e) / (1.f + e);
  return copysignf(r, x);
}

// L2-executed atomic add, returns old value (sc0 = return-old; no sc1 ->
// executes in XCD-local TCC; atomics bypass L1 by construction).
__device__ __forceinline__ int l2_add_ret(int* p, int v) {
  int old;
  asm volatile("global_atomic_add %0, %1, %2, off sc0\n\t"
               "s_waitcnt vmcnt(0)"
               : "=v"(old)
               : "v"((unsigned long long)(uintptr_t)p), "v"(v)
               : "memory");
  return old;
}
// L2-executed atomic add, fire-and-forget.
__device__ __forceinline__ void l2_add(int* p, int v) {
  asm volatile("global_atomic_add %0, %1, off"
               :: "v"((unsigned long long)(uintptr_t)p), "v"(v)
               : "memory");
}

// ---- prep: GT[n][k] = bf16 of (k<256 ? W_g[k][hc] : U_g[k-256][hc]), n=g*512+hc
__global__ void prep_gt(const float* __restrict__ Wi, const float* __restrict__ Ui,
                        const float* __restrict__ Wf, const float* __restrict__ Uf,
                        const float* __restrict__ Wc, const float* __restrict__ Uc,
                        const float* __restrict__ Wo, const float* __restrict__ Uo,
                        short* __restrict__ GT) {
  int idx = blockIdx.x * 256 + threadIdx.x;
  if (idx >= 2048 * KTOT) return;
  int n = idx / KTOT, k = idx % KTOT;
  int g = n >> 9, hc = n & 511;
  const float* W; const float* U;
  if (g == 0)      { W = Wi; U = Ui; }
  else if (g == 1) { W = Wf; U = Uf; }
  else if (g == 2) { W = Wc; U = Uc; }
  else             { W = Wo; U = Uo; }
  float v = (k < DIN) ? W[k * HID + hc] : U[(k - DIN) * HID + hc];
  GT[idx] = f2bf(v);
}

// ---- prep: x -> bf16 (4 elems/thread)
__global__ void prep_xb(const float* __restrict__ x, short* __restrict__ xb) {
  int idx = blockIdx.x * 256 + threadIdx.x;           // 4,194,304
  float4 v = ((const float4*)x)[idx];
  short4 o; o.x = f2bf(v.x); o.y = f2bf(v.y); o.z = f2bf(v.z); o.w = f2bf(v.w);
  ((short4*)xb)[idx] = o;
}

// ---- prep: h0 -> hbuf slot 0 (bf16)
__global__ void prep_h0(const float* __restrict__ h0, short* __restrict__ hbuf) {
  int idx = blockIdx.x * 256 + threadIdx.x;           // 65536
  hbuf[idx] = f2bf(h0[idx]);
}

// ---- prep: mdhp[b][h] = tanh(alpha@A - (beta*tspan)@B + theta@C)  (fp32)
__global__ void prep_mdhp(const float* __restrict__ alpha, const float* __restrict__ beta,
                          const float* __restrict__ theta, const float* __restrict__ tspan,
                          const float* __restrict__ A, const float* __restrict__ Bm,
                          const float* __restrict__ C, float* __restrict__ mdhp) {
  int idx = blockIdx.x * 256 + threadIdx.x;           // 65536
  int b = idx >> 9, h = idx & 511;
  float ts = tspan[b];
  float acc = 0.f;
  for (int k = 0; k < 256; ++k)
    acc += alpha[b * 256 + k] * A[k * HID + h] - ts * beta[b * 256 + k] * Bm[k * HID + h];
  for (int k = 0; k < 16; ++k)
    acc += theta[b * 16 + k] * C[k * HID + h];
  mdhp[idx] = tanhf(acc);
}

// ---- zero sync state (must run every launch: graph replays)
__global__ void zero_sync(int* __restrict__ cnt, int* __restrict__ cnt2,
                          unsigned* __restrict__ det) {
  int idx = blockIdx.x * 256 + threadIdx.x;           // grid 16*256 = 4096
  if (idx < NCHAIN * SEQ) { cnt[idx] = 0; cnt2[idx] = 0; }
  if (idx < 264) det[idx] = 0;
}

// ---- the persistent recurrence kernel --------------------------------------
__global__ __launch_bounds__(256, 1) void lstm_persist(
    const short* __restrict__ xb, const float* __restrict__ c0,
    const float* __restrict__ bi, const float* __restrict__ bf_,
    const float* __restrict__ bc, const float* __restrict__ bo,
    const short* __restrict__ GT, const float* __restrict__ mdhp,
    int* cnt, int* cnt2, unsigned* det, short* hbuf, float* out) {
  __shared__ __align__(16) short Bs[64 * BS_STRIDE];   // 99,328 B
  __shared__ float gbuf[2][4][16][17];                 // dbuf by t&1: 8,704 B
  __shared__ int wv[SEQ];                              // per-step wave counter
  __shared__ int ready;                                // latest step released
  __shared__ int s_mode;

  const int tid = threadIdx.x;
  const int wg = blockIdx.x;
  const int chain = wg & 7;        // XCD-local under round-robin wg->XCD
  const int j = wg >> 3;           // 0..31 column group

  // stage B^T slice: local row lr = g*16+c  <-  GT row n = g*512 + j*16 + c
  for (int idx = tid; idx < 64 * 384; idx += 256) {
    int lr = idx / 384, dw = idx % 384;
    int n = ((lr >> 4) << 9) + (j << 4) + (lr & 15);
    ((int*)Bs)[lr * 388 + dw] = ((const int*)GT)[n * 384 + dw];
  }
  for (int i = tid; i < SEQ; i += 256) wv[i] = 0;
  if (tid == 0) ready = 0;

  // per-thread epilogue state in registers
  const int er = tid >> 4, ec = tid & 15;
  const int brow = (chain << 4) + er, hcol = (j << 4) + ec;
  float creg = c0[brow * HID + hcol];
  const float mdv = mdhp[brow * HID + hcol];
  const float b0 = bi[hcol], b1 = bf_[hcol], b2 = bc[hcol], b3 = bo[hcol];

  // ---- XCD homogeneity detection (agent-scope; one-time) -------------------
  unsigned xid;
  asm volatile("s_getreg_b32 %0, hwreg(HW_REG_XCC_ID)" : "=s"(xid));
  xid &= 15u;
  if (tid == 0) {
    __hip_atomic_store(&det[wg], xid, __ATOMIC_RELAXED, __HIP_MEMORY_SCOPE_AGENT);
    __hip_atomic_fetch_add((int*)&det[256 + chain], 1, __ATOMIC_RELEASE,
                           __HIP_MEMORY_SCOPE_AGENT);
    while (__hip_atomic_load((int*)&det[256 + chain], __ATOMIC_ACQUIRE,
                             __HIP_MEMORY_SCOPE_AGENT) < NCOLW)
      __builtin_amdgcn_s_sleep(2);
    unsigned x0 = __hip_atomic_load(&det[chain], __ATOMIC_RELAXED,
                                    __HIP_MEMORY_SCOPE_AGENT);
    int ok = 1;
    for (int jj = 1; jj < NCOLW; ++jj)
      ok &= (__hip_atomic_load(&det[chain + 8 * jj], __ATOMIC_RELAXED,
                               __HIP_MEMORY_SCOPE_AGENT) == x0);
    s_mode = ok;
  }
  __syncthreads();                            // also covers Bs / wv staging
  const bool xloc = (s_mode != 0);

  const int lane = tid & 63;
  const int g = tid >> 6;                 // wave = gate
  const int mr = lane & 15;               // A-row / B-col within tile
  const int q = lane >> 4;                // quad
  const int bglob = (chain << 4) + mr;
  const short* Brow = &Bs[(g * 16 + mr) * BS_STRIDE + q * 8];
  int* mycnt = cnt + chain * SEQ;
  int* mycnt2 = cnt2 + chain * SEQ;
  bool esc = false;                       // sticky escape to agent polling

  for (int t = 0; t < SEQ; ++t) {
    // ---- issue x A-frag loads (h-independent; in flight across the poll)
    const short* xr = xb + ((size_t)t * BATCH + bglob) * DIN + q * 8;
    short8 xaf[8];
#pragma unroll
    for (int kk = 0; kk < 8; ++kk) xaf[kk] = *(const short8*)(xr + kk * 32);

    // ---- wait for h_{t-1}: tid0 polls L2 atomic, LDS fan-out to waves
    if (t > 0) {
      if (tid == 0) {
        int sp = 0;
        for (;;) {
          int v;
          if (xloc && !esc)
            v = l2_add_ret(&mycnt[t - 1], 0);       // XCD-L2 RMW, no hoisting
          else
            v = __hip_atomic_load(&mycnt2[t - 1], __ATOMIC_RELAXED,
                                  __HIP_MEMORY_SCOPE_AGENT);
          if (v >= NCOLW) break;
          __builtin_amdgcn_s_sleep(1);
          if (++sp > 4000) esc = true;    // deadlock-proof escape hatch
        }
        __hip_atomic_store(&ready, t, __ATOMIC_RELEASE,
                           __HIP_MEMORY_SCOPE_WORKGROUP);
      }
      while (__hip_atomic_load(&ready, __ATOMIC_ACQUIRE,
                               __HIP_MEMORY_SCOPE_WORKGROUP) < t) {}
      __builtin_amdgcn_sched_barrier(0);
    }

    // ---- issue h A-frag loads (slot t = h_{t-1}; fresh addr -> L1 cold,
    //      same-XCD L2 dirty-hit). Plain loads, proven r0/r2.
    const short* hr = hbuf + ((size_t)t * BATCH + bglob) * HID + q * 8;
    short8 haf[16];
#pragma unroll
    for (int kk = 0; kk < 16; ++kk) haf[kk] = *(const short8*)(hr + kk * 32);

    floatx4 ax  = {0.f, 0.f, 0.f, 0.f};
    floatx4 ah0 = {0.f, 0.f, 0.f, 0.f};
    floatx4 ah1 = {0.f, 0.f, 0.f, 0.f};

    // ---- x @ W MFMAs (overlap h-load latency)
#pragma unroll
    for (int kk = 0; kk < 8; ++kk)
      ax = __builtin_amdgcn_mfma_f32_16x16x32_bf16(
          xaf[kk], *(const short8*)(Brow + kk * 32), ax, 0, 0, 0);

    // ---- h loads landed (rule #18: waitcnt asm + sched_barrier)
    asm volatile("s_waitcnt vmcnt(0)" ::: "memory");
    __builtin_amdgcn_sched_barrier(0);

    // ---- h @ U MFMAs, two independent chains for latency
#pragma unroll
    for (int kk = 0; kk < 8; ++kk) {
      ah0 = __builtin_amdgcn_mfma_f32_16x16x32_bf16(
          haf[kk], *(const short8*)(Brow + DIN + kk * 32), ah0, 0, 0, 0);
      ah1 = __builtin_amdgcn_mfma_f32_16x16x32_bf16(
          haf[8 + kk], *(const short8*)(Brow + DIN + (8 + kk) * 32), ah1, 0, 0, 0);
    }

    // ---- epilogue: C/D layout col=lane&15, row=q*4+i (m89); gbuf dbuf'd
    const int p = t & 1;
#pragma unroll
    for (int i = 0; i < 4; ++i)
      gbuf[p][g][q * 4 + i][mr] = ax[i] + ah0[i] + ah1[i];
    __syncthreads();                         // the ONE barrier per step
    {
      float gi = gbuf[p][0][er][ec] + b0;
      float gf = gbuf[p][1][er][ec] + b1;
      float gc = gbuf[p][2][er][ec] + b2;
      float go = gbuf[p][3][er][ec] + b3;
      float it = fsig(gi), ft = fsig(gf), ot = fsig(go);
      float ch = ftanh(gc);
      float cn = mdv * (ft * creg + it * ch);
      creg = cn;
      float hv = ot * ftanh(cn);

      // bf16 h store to slot t+1 (skip at last step; slot 512 not allocated)
      if (t < SEQ - 1) {
        unsigned hb = (unsigned)(unsigned short)f2bf(hv);
        unsigned other = (unsigned)__shfl_xor((int)hb, 1, 64);
        if ((tid & 1) == 0) {
          unsigned pack = hb | (other << 16);
          size_t hidx = ((size_t)(t + 1) * BATCH + brow) * HID + hcol; // ec even
          if (xloc)
            *(unsigned*)&hbuf[hidx] = pack;     // plain -> shared XCD L2
          else
            __hip_atomic_store((unsigned*)&hbuf[hidx], pack, __ATOMIC_RELAXED,
                               __HIP_MEMORY_SCOPE_AGENT);
        }
      }

      // fp32 output (not read by consumers)
      size_t oidx = ((size_t)t * BATCH + brow) * HID + hcol;
      out[oidx] = hv;
      if (t == SEQ - 1) {
        size_t base = (size_t)SEQ * BATCH * HID;
        int e = brow * HID + hcol;
        out[base + e] = hv;                    // h_T
        out[base + BATCH * HID + e] = cn;      // c_T
      }
    }

    // ---- per-wave publish: drain stores, LDS count, last wave incs counters
    if (t < SEQ - 1) {
      asm volatile("s_waitcnt vmcnt(0)" ::: "memory");  // this wave's h landed
      if (lane == 0) {
        int old = __hip_atomic_fetch_add(&wv[t], 1, __ATOMIC_RELAXED,
                                         __HIP_MEMORY_SCOPE_WORKGROUP); // LDS
        if (old == 3) {                         // last wave of this WG
          if (xloc) {
            l2_add(&mycnt[t], 1);               // XCD-L2 flag
            __hip_atomic_fetch_add(&mycnt2[t], 1, __ATOMIC_RELAXED,
                                   __HIP_MEMORY_SCOPE_AGENT);   // shadow
          } else {
            __hip_atomic_fetch_add(&mycnt2[t], 1, __ATOMIC_RELEASE,
                                   __HIP_MEMORY_SCOPE_AGENT);
          }
        }
      }
    }
  }
}

// ---------------------------------------------------------------------------
extern "C" void kernel_launch(void* const* d_in, const int* in_sizes, int n_in,
                              void* d_out, int out_size, void* d_ws, size_t ws_size,
                              hipStream_t stream) {
  const float* x     = (const float*)d_in[0];
  const float* h0    = (const float*)d_in[1];
  const float* c0    = (const float*)d_in[2];
  const float* alpha = (const float*)d_in[3];
  const float* beta  = (const float*)d_in[4];
  const float* theta = (const float*)d_in[5];
  const float* tspan = (const float*)d_in[6];
  const float* Amd   = (const float*)d_in[7];
  const float* Bmd   = (const float*)d_in[8];
  const float* Cmd   = (const float*)d_in[9];
  const float* Wi = (const float*)d_in[10]; const float* Ui = (const float*)d_in[11];
  const float* bi = (const float*)d_in[12];
  const float* Wf = (const float*)d_in[13]; const float* Uf = (const float*)d_in[14];
  const float* bf_ = (const float*)d_in[15];
  const float* Wc = (const float*)d_in[16]; const float* Uc = (const float*)d_in[17];
  const float* bc = (const float*)d_in[18];
  const float* Wo = (const float*)d_in[19]; const float* Uo = (const float*)d_in[20];
  const float* bo = (const float*)d_in[21];

  float* out = (float*)d_out;
  char* ws = (char*)d_ws;
  // ws layout (bytes):
  short* GT     = (short*)ws;                         // @0           3,145,728
  float* mdhp   = (float*)(ws + 3145728);             // @3,145,728     262,144
  int*   cnt    = (int*)(ws + 3407872);               // @3,407,872      16,384
  int*   cnt2   = (int*)(ws + 3424256);               // @3,424,256      16,384
  unsigned* det = (unsigned*)(ws + 3440640);          // @3,440,640       4,096
  short* xb     = (short*)(ws + 3444736);             // @3,444,736  33,554,432
  short* hbuf   = (short*)(ws + 36999168);            // @36,999,168 67,108,864 (512 slots)
  // total: 104,108,032 B  (< 104,218,624 proven in round 0)

  zero_sync<<<16, 256, 0, stream>>>(cnt, cnt2, det);
  prep_gt<<<(2048 * KTOT + 255) / 256, 256, 0, stream>>>(Wi, Ui, Wf, Uf, Wc, Uc, Wo, Uo, GT);
  prep_xb<<<16384, 256, 0, stream>>>(x, xb);
  prep_h0<<<256, 256, 0, stream>>>(h0, hbuf);
  prep_mdhp<<<256, 256, 0, stream>>>(alpha, beta, theta, tspan, Amd, Bmd, Cmd, mdhp);
  lstm_persist<<<NCHAIN * NCOLW, 256, 0, stream>>>(xb, c0, bi, bf_, bc, bo,
                                                   GT, mdhp, cnt, cnt2, det, hbuf, out);
}

// Round 4
// 2330.686 us; speedup vs baseline: 9.7862x; 1.0314x over previous
//
#include <hip/hip_runtime.h>
#include <cstdint>
#include <cstddef>

// ---------------------------------------------------------------------------
// MDHP-LSTM on MI355X.  S=512, B=128, D=256, H=512.
// Round-6: data-IS-the-flag. Evidence base:
//   * r0 vs r3: agent C++ atomics == asm L2 atomics == 4 us/step -> RMW
//     atomics execute at IF regardless of scope bits; flags can't go faster.
//   * r2: plain store -> same-XCD L2 -> sc0 load is correct & L2-resident
//     (WRITE_SIZE 140MB signature) and sc0 loads bypass L1 (ring reuse
//     passed). This is the only proven L2-speed channel.
// Protocol: hbuf prefilled with 0xFFFFFFFF (bf16 NaN pair, unreachable from
// f2bf). Producers plain-store packed dwords; consumers poll their own
// A-fragments with sc0 loads until no NaN word remains. No RMW, no flag
// indirection in the steady state. Insurance: producers still publish
// agent-scope cnt2[t]; a consumer stuck >20k polls escapes (sticky) to
// flag-wait. !xloc chains use flag-wait + sc0 sc1 (IF) loads throughout.
// ---------------------------------------------------------------------------

typedef __attribute__((ext_vector_type(8))) short short8;
typedef __attribute__((ext_vector_type(4))) float floatx4;

#define SEQ 512
#define BATCH 128
#define DIN 256
#define HID 512
#define KTOT 768
#define NCHAIN 8
#define NCOLW 32
#define BS_STRIDE 776         // shorts per LDS B-row (768 + 8 pad, 16B aligned)

__device__ __forceinline__ short f2bf(float f) {
  union { float f; unsigned u; } v; v.f = f;
  unsigned u = v.u + 0x7fffu + ((v.u >> 16) & 1u);   // RNE
  return (short)(u >> 16);
}
__device__ __forceinline__ float fsig(float x) {
  return 1.f / (1.f + __expf(-x));
}
__device__ __forceinline__ float ftanh(float x) {
  float a = fabsf(x);
  float e = __expf(-2.f * a);
  float r = (1.f - e) / (1.f + e);
  return copysignf(r, x);
}
__device__ __forceinline__ unsigned umax2(unsigned a, unsigned b) {
  return a > b ? a : b;
}

// 16 A-frag loads + vmcnt(0) in ONE asm block (rule 18: sched_barrier after).
// sc0 = L1-bypass, served by XCD L2 (r2-proven).
__device__ __forceinline__ void hload16_sc0(const short* hr, short8 (&haf)[16]) {
  asm volatile(
      "global_load_dwordx4 %0,  %16, off sc0\n\t"
      "global_load_dwordx4 %1,  %16, off offset:64 sc0\n\t"
      "global_load_dwordx4 %2,  %16, off offset:128 sc0\n\t"
      "global_load_dwordx4 %3,  %16, off offset:192 sc0\n\t"
      "global_load_dwordx4 %4,  %16, off offset:256 sc0\n\t"
      "global_load_dwordx4 %5,  %16, off offset:320 sc0\n\t"
      "global_load_dwordx4 %6,  %16, off offset:384 sc0\n\t"
      "global_load_dwordx4 %7,  %16, off offset:448 sc0\n\t"
      "global_load_dwordx4 %8,  %16, off offset:512 sc0\n\t"
      "global_load_dwordx4 %9,  %16, off offset:576 sc0\n\t"
      "global_load_dwordx4 %10, %16, off offset:640 sc0\n\t"
      "global_load_dwordx4 %11, %16, off offset:704 sc0\n\t"
      "global_load_dwordx4 %12, %16, off offset:768 sc0\n\t"
      "global_load_dwordx4 %13, %16, off offset:832 sc0\n\t"
      "global_load_dwordx4 %14, %16, off offset:896 sc0\n\t"
      "global_load_dwordx4 %15, %16, off offset:960 sc0\n\t"
      "s_waitcnt vmcnt(0)"
      : "=v"(haf[0]), "=v"(haf[1]), "=v"(haf[2]), "=v"(haf[3]),
        "=v"(haf[4]), "=v"(haf[5]), "=v"(haf[6]), "=v"(haf[7]),
        "=v"(haf[8]), "=v"(haf[9]), "=v"(haf[10]), "=v"(haf[11]),
        "=v"(haf[12]), "=v"(haf[13]), "=v"(haf[14]), "=v"(haf[15])
      : "v"((unsigned long long)(uintptr_t)hr)
      : "memory");
}
// IF-coherent variant (L1+L2 bypass) for cross-XCD fallback.
__device__ __forceinline__ void hload16_bypass(const short* hr, short8 (&haf)[16]) {
  asm volatile(
      "global_load_dwordx4 %0,  %16, off sc0 sc1\n\t"
      "global_load_dwordx4 %1,  %16, off offset:64 sc0 sc1\n\t"
      "global_load_dwordx4 %2,  %16, off offset:128 sc0 sc1\n\t"
      "global_load_dwordx4 %3,  %16, off offset:192 sc0 sc1\n\t"
      "global_load_dwordx4 %4,  %16, off offset:256 sc0 sc1\n\t"
      "global_load_dwordx4 %5,  %16, off offset:320 sc0 sc1\n\t"
      "global_load_dwordx4 %6,  %16, off offset:384 sc0 sc1\n\t"
      "global_load_dwordx4 %7,  %16, off offset:448 sc0 sc1\n\t"
      "global_load_dwordx4 %8,  %16, off offset:512 sc0 sc1\n\t"
      "global_load_dwordx4 %9,  %16, off offset:576 sc0 sc1\n\t"
      "global_load_dwordx4 %10, %16, off offset:640 sc0 sc1\n\t"
      "global_load_dwordx4 %11, %16, off offset:704 sc0 sc1\n\t"
      "global_load_dwordx4 %12, %16, off offset:768 sc0 sc1\n\t"
      "global_load_dwordx4 %13, %16, off offset:832 sc0 sc1\n\t"
      "global_load_dwordx4 %14, %16, off offset:896 sc0 sc1\n\t"
      "global_load_dwordx4 %15, %16, off offset:960 sc0 sc1\n\t"
      "s_waitcnt vmcnt(0)"
      : "=v"(haf[0]), "=v"(haf[1]), "=v"(haf[2]), "=v"(haf[3]),
        "=v"(haf[4]), "=v"(haf[5]), "=v"(haf[6]), "=v"(haf[7]),
        "=v"(haf[8]), "=v"(haf[9]), "=v"(haf[10]), "=v"(haf[11]),
        "=v"(haf[12]), "=v"(haf[13]), "=v"(haf[14]), "=v"(haf[15])
      : "v"((unsigned long long)(uintptr_t)hr)
      : "memory");
}

__device__ __forceinline__ unsigned nan_max(const short8 (&haf)[16]) {
  unsigned m = 0;
#pragma unroll
  for (int kk = 0; kk < 16; ++kk) {
    unsigned w[4];
    __builtin_memcpy(w, &haf[kk], 16);
    m = umax2(m, umax2(umax2(w[0], w[1]), umax2(w[2], w[3])));
  }
  return m;
}

// ---- prep: GT[n][k] = bf16 of (k<256 ? W_g[k][hc] : U_g[k-256][hc]), n=g*512+hc
__global__ void prep_gt(const float* __restrict__ Wi, const float* __restrict__ Ui,
                        const float* __restrict__ Wf, const float* __restrict__ Uf,
                        const float* __restrict__ Wc, const float* __restrict__ Uc,
                        const float* __restrict__ Wo, const float* __restrict__ Uo,
                        short* __restrict__ GT) {
  int idx = blockIdx.x * 256 + threadIdx.x;
  if (idx >= 2048 * KTOT) return;
  int n = idx / KTOT, k = idx % KTOT;
  int g = n >> 9, hc = n & 511;
  const float* W; const float* U;
  if (g == 0)      { W = Wi; U = Ui; }
  else if (g == 1) { W = Wf; U = Uf; }
  else if (g == 2) { W = Wc; U = Uc; }
  else             { W = Wo; U = Uo; }
  float v = (k < DIN) ? W[k * HID + hc] : U[(k - DIN) * HID + hc];
  GT[idx] = f2bf(v);
}

// ---- prep: x -> bf16 (4 elems/thread)
__global__ void prep_xb(const float* __restrict__ x, short* __restrict__ xb) {
  int idx = blockIdx.x * 256 + threadIdx.x;           // 4,194,304
  float4 v = ((const float4*)x)[idx];
  short4 o; o.x = f2bf(v.x); o.y = f2bf(v.y); o.z = f2bf(v.z); o.w = f2bf(v.w);
  ((short4*)xb)[idx] = o;
}

// ---- prep: fill hbuf with NaN sentinel (16B/thread over 67,108,864 B)
__global__ void fill_nan(uint4* __restrict__ hb) {
  int idx = blockIdx.x * 256 + threadIdx.x;           // 4,194,304
  uint4 v; v.x = 0xFFFFFFFFu; v.y = 0xFFFFFFFFu; v.z = 0xFFFFFFFFu; v.w = 0xFFFFFFFFu;
  hb[idx] = v;
}

// ---- prep: h0 -> hbuf slot 0 (bf16); runs AFTER fill_nan (stream order)
__global__ void prep_h0(const float* __restrict__ h0, short* __restrict__ hbuf) {
  int idx = blockIdx.x * 256 + threadIdx.x;           // 65536
  hbuf[idx] = f2bf(h0[idx]);
}

// ---- prep: mdhp[b][h] = tanh(alpha@A - (beta*tspan)@B + theta@C)  (fp32)
__global__ void prep_mdhp(const float* __restrict__ alpha, const float* __restrict__ beta,
                          const float* __restrict__ theta, const float* __restrict__ tspan,
                          const float* __restrict__ A, const float* __restrict__ Bm,
                          const float* __restrict__ C, float* __restrict__ mdhp) {
  int idx = blockIdx.x * 256 + threadIdx.x;           // 65536
  int b = idx >> 9, h = idx & 511;
  float ts = tspan[b];
  float acc = 0.f;
  for (int k = 0; k < 256; ++k)
    acc += alpha[b * 256 + k] * A[k * HID + h] - ts * beta[b * 256 + k] * Bm[k * HID + h];
  for (int k = 0; k < 16; ++k)
    acc += theta[b * 16 + k] * C[k * HID + h];
  mdhp[idx] = tanhf(acc);
}

// ---- zero sync state (must run every launch: graph replays)
__global__ void zero_sync(int* __restrict__ cnt2, unsigned* __restrict__ det) {
  int idx = blockIdx.x * 256 + threadIdx.x;           // grid 16*256 = 4096
  if (idx < NCHAIN * SEQ) cnt2[idx] = 0;
  if (idx < 264) det[idx] = 0;
}

// ---- the persistent recurrence kernel --------------------------------------
__global__ __launch_bounds__(256, 1) void lstm_persist(
    const short* __restrict__ xb, const float* __restrict__ c0,
    const float* __restrict__ bi, const float* __restrict__ bf_,
    const float* __restrict__ bc, const float* __restrict__ bo,
    const short* __restrict__ GT, const float* __restrict__ mdhp,
    int* cnt2, unsigned* det, short* hbuf, float* out) {
  __shared__ __align__(16) short Bs[64 * BS_STRIDE];   // 99,328 B
  __shared__ float gbuf[2][4][16][17];                 // dbuf by t&1: 8,704 B
  __shared__ int wv[SEQ];                              // per-step wave counter
  __shared__ int s_mode;

  const int tid = threadIdx.x;
  const int wg = blockIdx.x;
  const int chain = wg & 7;        // XCD-local under round-robin wg->XCD
  const int j = wg >> 3;           // 0..31 column group

  // stage B^T slice: local row lr = g*16+c  <-  GT row n = g*512 + j*16 + c
  for (int idx = tid; idx < 64 * 384; idx += 256) {
    int lr = idx / 384, dw = idx % 384;
    int n = ((lr >> 4) << 9) + (j << 4) + (lr & 15);
    ((int*)Bs)[lr * 388 + dw] = ((const int*)GT)[n * 384 + dw];
  }
  for (int i = tid; i < SEQ; i += 256) wv[i] = 0;

  // per-thread epilogue state in registers
  const int er = tid >> 4, ec = tid & 15;
  const int brow = (chain << 4) + er, hcol = (j << 4) + ec;
  float creg = c0[brow * HID + hcol];
  const float mdv = mdhp[brow * HID + hcol];
  const float b0 = bi[hcol], b1 = bf_[hcol], b2 = bc[hcol], b3 = bo[hcol];

  // ---- XCD homogeneity detection (agent-scope; one-time) -------------------
  unsigned xid;
  asm volatile("s_getreg_b32 %0, hwreg(HW_REG_XCC_ID)" : "=s"(xid));
  xid &= 15u;
  if (tid == 0) {
    __hip_atomic_store(&det[wg], xid, __ATOMIC_RELAXED, __HIP_MEMORY_SCOPE_AGENT);
    __hip_atomic_fetch_add((int*)&det[256 + chain], 1, __ATOMIC_RELEASE,
                           __HIP_MEMORY_SCOPE_AGENT);
    while (__hip_atomic_load((int*)&det[256 + chain], __ATOMIC_ACQUIRE,
                             __HIP_MEMORY_SCOPE_AGENT) < NCOLW)
      __builtin_amdgcn_s_sleep(2);
    unsigned x0 = __hip_atomic_load(&det[chain], __ATOMIC_RELAXED,
                                    __HIP_MEMORY_SCOPE_AGENT);
    int ok = 1;
    for (int jj = 1; jj < NCOLW; ++jj)
      ok &= (__hip_atomic_load(&det[chain + 8 * jj], __ATOMIC_RELAXED,
                               __HIP_MEMORY_SCOPE_AGENT) == x0);
    s_mode = ok;
  }
  __syncthreads();                            // also covers Bs / wv staging
  const bool xloc = (s_mode != 0);

  const int lane = tid & 63;
  const int g = tid >> 6;                 // wave = gate
  const int mr = lane & 15;               // A-row / B-col within tile
  const int q = lane >> 4;                // quad
  const int bglob = (chain << 4) + mr;
  const short* Brow = &Bs[(g * 16 + mr) * BS_STRIDE + q * 8];
  int* mycnt2 = cnt2 + chain * SEQ;
  bool esc = !xloc;                       // fallback/escape: flag-gated loads

  for (int t = 0; t < SEQ; ++t) {
    // ---- issue x A-frag loads (h-independent; drain via poll's vmcnt(0))
    const short* xr = xb + ((size_t)t * BATCH + bglob) * DIN + q * 8;
    short8 xaf[8];
#pragma unroll
    for (int kk = 0; kk < 8; ++kk) xaf[kk] = *(const short8*)(xr + kk * 32);

    // ---- acquire h_{t-1} (slot t): data-poll, per wave, no flags ----------
    const short* hr = hbuf + ((size_t)t * BATCH + bglob) * HID + q * 8;
    short8 haf[16];
    int att = 0;
    for (;;) {
      if (!esc) {
        hload16_sc0(hr, haf);
        if (!__any(nan_max(haf) == 0xFFFFFFFFu)) break;
        if (++att > 20000) esc = true;    // sticky, bounded (insurance)
      } else {
        if (t > 0) {
          while (__hip_atomic_load(&mycnt2[t - 1], __ATOMIC_RELAXED,
                                   __HIP_MEMORY_SCOPE_AGENT) < NCOLW)
            __builtin_amdgcn_s_sleep(1);
        }
        if (xloc) {                       // escaped but same-XCD: L2 serves
          hload16_sc0(hr, haf);
          if (!__any(nan_max(haf) == 0xFFFFFFFFu)) break;
        } else {                          // cross-XCD: IF-coherent loads
          hload16_bypass(hr, haf);
          break;
        }
      }
    }
    __builtin_amdgcn_sched_barrier(0);    // rule 18: pin MFMAs after vmcnt

    floatx4 ax  = {0.f, 0.f, 0.f, 0.f};
    floatx4 ah0 = {0.f, 0.f, 0.f, 0.f};
    floatx4 ah1 = {0.f, 0.f, 0.f, 0.f};

    // ---- x @ W MFMAs
#pragma unroll
    for (int kk = 0; kk < 8; ++kk)
      ax = __builtin_amdgcn_mfma_f32_16x16x32_bf16(
          xaf[kk], *(const short8*)(Brow + kk * 32), ax, 0, 0, 0);

    // ---- h @ U MFMAs, two independent chains for latency
#pragma unroll
    for (int kk = 0; kk < 8; ++kk) {
      ah0 = __builtin_amdgcn_mfma_f32_16x16x32_bf16(
          haf[kk], *(const short8*)(Brow + DIN + kk * 32), ah0, 0, 0, 0);
      ah1 = __builtin_amdgcn_mfma_f32_16x16x32_bf16(
          haf[8 + kk], *(const short8*)(Brow + DIN + (8 + kk) * 32), ah1, 0, 0, 0);
    }

    // ---- epilogue: C/D layout col=lane&15, row=q*4+i (m89); gbuf dbuf'd
    const int p = t & 1;
#pragma unroll
    for (int i = 0; i < 4; ++i)
      gbuf[p][g][q * 4 + i][mr] = ax[i] + ah0[i] + ah1[i];
    __syncthreads();                         // the ONE barrier per step
    {
      float gi = gbuf[p][0][er][ec] + b0;
      float gf = gbuf[p][1][er][ec] + b1;
      float gc = gbuf[p][2][er][ec] + b2;
      float go = gbuf[p][3][er][ec] + b3;
      float it = fsig(gi), ft = fsig(gf), ot = fsig(go);
      float ch = ftanh(gc);
      float cn = mdv * (ft * creg + it * ch);
      creg = cn;
      float hv = ot * ftanh(cn);

      // bf16 h store to slot t+1: pair lanes -> one 4B word (dword-atomic)
      if (t < SEQ - 1) {
        unsigned hb = (unsigned)(unsigned short)f2bf(hv);
        unsigned other = (unsigned)__shfl_xor((int)hb, 1, 64);
        if ((tid & 1) == 0) {
          unsigned pack = hb | (other << 16);
          size_t hidx = ((size_t)(t + 1) * BATCH + brow) * HID + hcol; // ec even
          if (xloc)
            *(unsigned*)&hbuf[hidx] = pack;     // plain -> shared XCD L2
          else
            __hip_atomic_store((unsigned*)&hbuf[hidx], pack, __ATOMIC_RELAXED,
                               __HIP_MEMORY_SCOPE_AGENT);
        }
      }

      // fp32 output (not read by consumers)
      size_t oidx = ((size_t)t * BATCH + brow) * HID + hcol;
      out[oidx] = hv;
      if (t == SEQ - 1) {
        size_t base = (size_t)SEQ * BATCH * HID;
        int e = brow * HID + hcol;
        out[base + e] = hv;                    // h_T
        out[base + BATCH * HID + e] = cn;      // c_T
      }
    }

    // ---- insurance publish: per-wave drain -> LDS count -> agent flag
    if (t < SEQ - 1) {
      asm volatile("s_waitcnt vmcnt(0)" ::: "memory");  // this wave's h landed
      if (lane == 0) {
        int old = __hip_atomic_fetch_add(&wv[t], 1, __ATOMIC_RELAXED,
                                         __HIP_MEMORY_SCOPE_WORKGROUP); // LDS
        if (old == 3)                           // last wave of this WG
          __hip_atomic_fetch_add(&mycnt2[t], 1, __ATOMIC_RELAXED,
                                 __HIP_MEMORY_SCOPE_AGENT);
      }
    }
  }
}

// ---------------------------------------------------------------------------
extern "C" void kernel_launch(void* const* d_in, const int* in_sizes, int n_in,
                              void* d_out, int out_size, void* d_ws, size_t ws_size,
                              hipStream_t stream) {
  const float* x     = (const float*)d_in[0];
  const float* h0    = (const float*)d_in[1];
  const float* c0    = (const float*)d_in[2];
  const float* alpha = (const float*)d_in[3];
  const float* beta  = (const float*)d_in[4];
  const float* theta = (const float*)d_in[5];
  const float* tspan = (const float*)d_in[6];
  const float* Amd   = (const float*)d_in[7];
  const float* Bmd   = (const float*)d_in[8];
  const float* Cmd   = (const float*)d_in[9];
  const float* Wi = (const float*)d_in[10]; const float* Ui = (const float*)d_in[11];
  const float* bi = (const float*)d_in[12];
  const float* Wf = (const float*)d_in[13]; const float* Uf = (const float*)d_in[14];
  const float* bf_ = (const float*)d_in[15];
  const float* Wc = (const float*)d_in[16]; const float* Uc = (const float*)d_in[17];
  const float* bc = (const float*)d_in[18];
  const float* Wo = (const float*)d_in[19]; const float* Uo = (const float*)d_in[20];
  const float* bo = (const float*)d_in[21];

  float* out = (float*)d_out;
  char* ws = (char*)d_ws;
  // ws layout (bytes):
  short* GT     = (short*)ws;                         // @0            3,145,728
  float* mdhp   = (float*)(ws + 3145728);             // @3,145,728      262,144
  int*   cnt2   = (int*)(ws + 3407872);               // @3,407,872       16,384
  unsigned* det = (unsigned*)(ws + 3424256);          // @3,424,256        4,096
  short* xb     = (short*)(ws + 3428352);             // @3,428,352   33,554,432
  short* hbuf   = (short*)(ws + 36982784);            // @36,982,784  67,108,864
  // total: 104,091,648 B  (< 104,218,624 proven in round 0)

  zero_sync<<<16, 256, 0, stream>>>(cnt2, det);
  prep_gt<<<(2048 * KTOT + 255) / 256, 256, 0, stream>>>(Wi, Ui, Wf, Uf, Wc, Uc, Wo, Uo, GT);
  fill_nan<<<16384, 256, 0, stream>>>((uint4*)hbuf);
  prep_xb<<<16384, 256, 0, stream>>>(x, xb);
  prep_h0<<<256, 256, 0, stream>>>(h0, hbuf);       // after fill_nan: slot 0 real
  prep_mdhp<<<256, 256, 0, stream>>>(alpha, beta, theta, tspan, Amd, Bmd, Cmd, mdhp);
  lstm_persist<<<NCHAIN * NCOLW, 256, 0, stream>>>(xb, c0, bi, bf_, bc, bo,
                                                   GT, mdhp, cnt2, det, hbuf, out);
}